// Round 7
// baseline (315.807 us; speedup 1.0000x reference)
//
#include <hip/hip_runtime.h>
#include <math.h>

#define B_      16
#define H_      32
#define KVH_    8
#define G_      4
#define D_      128
#define BS_     16
#define L_      4096
#define MAXB_   256
#define T_      4096
#define PARTN_  32            // tokens per partition (one block)
#define NP_     (T_ / PARTN_) // 128 partitions per sequence
#define GT_     4             // tokens per staged group
#define TPAD_   1032          // padded floats per token segment (1024 + 8)
#define SCALE_  0.08838834764831843f

__device__ __forceinline__ int seq_len_of(int ctx) {
  return (ctx >= L_) ? (L_ - BS_ + (ctx & (BS_ - 1)) + 1) : (ctx + 1);
}

// Kernel 1: RoPE table, [T][64] pairs of (cos, sin) interleaved.
__global__ void rope_table_kernel(float* __restrict__ tab) {
  int idx = blockIdx.x * blockDim.x + threadIdx.x;
  if (idx >= T_ * 64) return;
  int t = idx >> 6, i = idx & 63;
  double inv = pow(10000.0, -(double)(2 * i) / 128.0);
  float ang = (float)t * (float)inv;   // f32 argument, like the reference
  double a = (double)ang;
  tab[2 * idx]     = (float)cos(a);
  tab[2 * idx + 1] = (float)sin(a);
}

// Kernel 2: one 512-thread block (8 waves) per (b, 32-token partition),
// covering ALL 8 kv-heads. Per 4-token group the block streams K (16 KB
// CONTIGUOUS) + V (16 KB CONTIGUOUS) into double-buffered LDS with an
// async-STAGE split (issue loads -> compute current from LDS -> ds_write
// -> barrier). Wave w computes kvh w: 16 lanes per token, 4 tokens/iter;
// lane dg holds dims [4dg..4dg+3] and [64+4dg..64+4dg+3] (RoPE-pair local).
__global__ __launch_bounds__(512, 4) void attn_partial_kernel(
    const float* __restrict__ q, const float* __restrict__ knew,
    const float* __restrict__ vnew, const float* __restrict__ kc,
    const float* __restrict__ vc, const int* __restrict__ btab,
    const int* __restrict__ ctxl, const float* __restrict__ tab,
    float* __restrict__ opart, float2* __restrict__ ml) {
  int bid  = blockIdx.x;
  int part = bid & (NP_ - 1);
  int b    = bid >> 7;                   // NP_ == 128

  int seq = seq_len_of(ctxl[b]);
  int t0 = part * PARTN_;
  if (t0 >= seq) return;                 // block-uniform: safe (pre-barrier)
  int t1 = min(t0 + PARTN_, seq);
  int posq = seq - 1;
  int nG = (t1 - t0 + GT_ - 1) >> 2;

  int tid  = threadIdx.x;
  int kvh  = tid >> 6;                   // wave index == kv head
  int lane = tid & 63;
  int tsub = lane >> 4;
  int dg   = lane & 15;
  int pidx = ((b * KVH_ + kvh) * NP_ + part) * G_;

  // two cache-block ids cover the 32-token partition
  int2 bt = *(const int2*)(btab + b * MAXB_ + (t0 >> 4));

  __shared__ float lds[2][2][GT_ * TPAD_];   // [buf][K/V][token*TPAD_+f]

  const float4* tab4 = (const float4*)tab;

  // per-lane cos/sin at first owned position; rotation constants (row 4)
  int tstart = t0 + tsub;
  float4 cc0 = tab4[tstart * 32 + 2 * dg];
  float4 cc1 = tab4[tstart * 32 + 2 * dg + 1];
  float4 r0  = tab4[4 * 32 + 2 * dg];
  float4 r1  = tab4[4 * 32 + 2 * dg + 1];

  // roped + scaled q fragments for the 4 heads of this kv group
  float q1[G_][4], q2[G_][4];
  {
    float4 cq0 = tab4[posq * 32 + 2 * dg];
    float4 cq1 = tab4[posq * 32 + 2 * dg + 1];
#pragma unroll
    for (int g = 0; g < G_; ++g) {
      const float* qp = q + b * (H_ * D_) + (kvh * G_ + g) * D_;
      float4 a  = *(const float4*)(qp + 4 * dg);
      float4 bq = *(const float4*)(qp + 64 + 4 * dg);
      q1[g][0] = (a.x * cq0.x - bq.x * cq0.y) * SCALE_;
      q2[g][0] = (bq.x * cq0.x + a.x * cq0.y) * SCALE_;
      q1[g][1] = (a.y * cq0.z - bq.y * cq0.w) * SCALE_;
      q2[g][1] = (bq.y * cq0.z + a.y * cq0.w) * SCALE_;
      q1[g][2] = (a.z * cq1.x - bq.z * cq1.y) * SCALE_;
      q2[g][2] = (bq.z * cq1.x + a.z * cq1.y) * SCALE_;
      q1[g][3] = (a.w * cq1.z - bq.w * cq1.w) * SCALE_;
      q2[g][3] = (bq.w * cq1.z + a.w * cq1.w) * SCALE_;
    }
  }

  float m[G_], l[G_], acc[G_][8];
#pragma unroll
  for (int g = 0; g < G_; ++g) {
    m[g] = -1e30f; l[g] = 0.f;
#pragma unroll
    for (int j = 0; j < 8; ++j) acc[g][j] = 0.f;
  }

  // -------- staging helpers (contiguous global <-> padded LDS) --------
  float4 s0, s1, s2, s3;                 // in-flight staging registers
  auto stage_load = [&](int gi) {        // issue 4x global_load_dwordx4
    int tg   = t0 + gi * GT_;
    int blk  = (gi & 4) ? bt.y : bt.x;   // gi>>2 selects cache block
    int slot = tg & (BS_ - 1);
    size_t base = (size_t)(blk * BS_ + slot) * (KVH_ * D_);
    const float4* kg = (const float4*)(kc + base);
    const float4* vg = (const float4*)(vc + base);
    s0 = kg[tid];  s1 = kg[tid + 512];   // 16 KB K, perfectly contiguous
    s2 = vg[tid];  s3 = vg[tid + 512];   // 16 KB V, perfectly contiguous
  };
  auto stage_write = [&](int buf) {
    int a0 = ((tid)       >> 8) * TPAD_ + (((tid)       & 255) << 2);
    int a1 = ((tid + 512) >> 8) * TPAD_ + (((tid + 512) & 255) << 2);
    *(float4*)&lds[buf][0][a0] = s0;
    *(float4*)&lds[buf][0][a1] = s1;
    *(float4*)&lds[buf][1][a0] = s2;
    *(float4*)&lds[buf][1][a1] = s3;
  };

  auto compute = [&](int buf, int tg) {
    int aK = tsub * TPAD_ + kvh * D_ + 4 * dg;
    float4 ka = *(const float4*)&lds[buf][0][aK];
    float4 kb = *(const float4*)&lds[buf][0][aK + 64];
    float4 va = *(const float4*)&lds[buf][1][aK];
    float4 vb = *(const float4*)&lds[buf][1][aK + 64];
    int tt = tg + tsub;
    float kr1[4], kr2[4];
    kr1[0] = ka.x * cc0.x - kb.x * cc0.y;  kr2[0] = kb.x * cc0.x + ka.x * cc0.y;
    kr1[1] = ka.y * cc0.z - kb.y * cc0.w;  kr2[1] = kb.y * cc0.z + ka.y * cc0.w;
    kr1[2] = ka.z * cc1.x - kb.z * cc1.y;  kr2[2] = kb.z * cc1.x + ka.z * cc1.y;
    kr1[3] = ka.w * cc1.z - kb.w * cc1.w;  kr2[3] = kb.w * cc1.z + ka.w * cc1.w;
    bool valid = (tt < t1) & (tt != posq);
    float s[G_];
#pragma unroll
    for (int g = 0; g < G_; ++g) {
      s[g] = kr1[0] * q1[g][0] + kr2[0] * q2[g][0]
           + kr1[1] * q1[g][1] + kr2[1] * q2[g][1]
           + kr1[2] * q1[g][2] + kr2[2] * q2[g][2]
           + kr1[3] * q1[g][3] + kr2[3] * q2[g][3];
    }
#pragma unroll
    for (int off = 1; off <= 8; off <<= 1) {
#pragma unroll
      for (int g = 0; g < G_; ++g) s[g] += __shfl_xor(s[g], off);
    }
#pragma unroll
    for (int g = 0; g < G_; ++g) {
      float sv   = valid ? s[g] : -1e30f;
      float mn   = fmaxf(m[g], sv);
      float corr = __expf(m[g] - mn);
      float p    = __expf(sv - mn);
      p = valid ? p : 0.0f;
      m[g] = mn;
      l[g] = l[g] * corr + p;
      acc[g][0] = acc[g][0] * corr + p * va.x;
      acc[g][1] = acc[g][1] * corr + p * va.y;
      acc[g][2] = acc[g][2] * corr + p * va.z;
      acc[g][3] = acc[g][3] * corr + p * va.w;
      acc[g][4] = acc[g][4] * corr + p * vb.x;
      acc[g][5] = acc[g][5] * corr + p * vb.y;
      acc[g][6] = acc[g][6] * corr + p * vb.z;
      acc[g][7] = acc[g][7] * corr + p * vb.w;
    }
    // advance cos/sin by 4*theta (angle addition)
    float nc;
    nc = cc0.x * r0.x - cc0.y * r0.y;
    cc0.y = cc0.y * r0.x + cc0.x * r0.y; cc0.x = nc;
    nc = cc0.z * r0.z - cc0.w * r0.w;
    cc0.w = cc0.w * r0.z + cc0.z * r0.w; cc0.z = nc;
    nc = cc1.x * r1.x - cc1.y * r1.y;
    cc1.y = cc1.y * r1.x + cc1.x * r1.y; cc1.x = nc;
    nc = cc1.z * r1.z - cc1.w * r1.w;
    cc1.w = cc1.w * r1.z + cc1.z * r1.w; cc1.z = nc;
  };

  // -------- main loop: prologue stage, then {issue, compute, write, bar} --
  stage_load(0);
  stage_write(0);
  __syncthreads();
  int cur = 0;
  int nGm1 = nG - 1;
  for (int gi = 0; gi < nG; ++gi) {
    stage_load(min(gi + 1, nGm1));       // unconditional: clamped, valid mem
    compute(cur, t0 + gi * GT_);
    stage_write(cur ^ 1);                // last iter writes unread buffer
    __syncthreads();
    cur ^= 1;
  }

  // current-token contribution (the one partition owning posq), lanes 0-15
  if (lane < 16 && posq >= t0 && posq < t1) {
    const float* kp = knew + (b * KVH_ + kvh) * D_;
    float4 xa = *(const float4*)(kp + 4 * dg);
    float4 xb = *(const float4*)(kp + 64 + 4 * dg);
    float4 p0 = tab4[posq * 32 + 2 * dg];
    float4 p1 = tab4[posq * 32 + 2 * dg + 1];
    float kr1[4], kr2[4];
    kr1[0] = xa.x * p0.x - xb.x * p0.y;  kr2[0] = xb.x * p0.x + xa.x * p0.y;
    kr1[1] = xa.y * p0.z - xb.y * p0.w;  kr2[1] = xb.y * p0.z + xa.y * p0.w;
    kr1[2] = xa.z * p1.x - xb.z * p1.y;  kr2[2] = xb.z * p1.x + xa.z * p1.y;
    kr1[3] = xa.w * p1.z - xb.w * p1.w;  kr2[3] = xb.w * p1.z + xa.w * p1.w;
    const float* vp = vnew + (b * KVH_ + kvh) * D_;
    float4 va = *(const float4*)(vp + 4 * dg);
    float4 vb = *(const float4*)(vp + 64 + 4 * dg);
    float s[G_];
#pragma unroll
    for (int g = 0; g < G_; ++g) {
      s[g] = kr1[0] * q1[g][0] + kr2[0] * q2[g][0]
           + kr1[1] * q1[g][1] + kr2[1] * q2[g][1]
           + kr1[2] * q1[g][2] + kr2[2] * q2[g][2]
           + kr1[3] * q1[g][3] + kr2[3] * q2[g][3];
    }
#pragma unroll
    for (int off = 1; off <= 8; off <<= 1) {
#pragma unroll
      for (int g = 0; g < G_; ++g) s[g] += __shfl_xor(s[g], off);
    }
#pragma unroll
    for (int g = 0; g < G_; ++g) {
      float sv   = s[g];
      float mn   = fmaxf(m[g], sv);
      float corr = __expf(m[g] - mn);
      float p    = __expf(sv - mn);
      m[g] = mn;
      l[g] = l[g] * corr + p;
      acc[g][0] = acc[g][0] * corr + p * va.x;
      acc[g][1] = acc[g][1] * corr + p * va.y;
      acc[g][2] = acc[g][2] * corr + p * va.z;
      acc[g][3] = acc[g][3] * corr + p * va.w;
      acc[g][4] = acc[g][4] * corr + p * vb.x;
      acc[g][5] = acc[g][5] * corr + p * vb.y;
      acc[g][6] = acc[g][6] * corr + p * vb.z;
      acc[g][7] = acc[g][7] * corr + p * vb.w;
    }
  }

  // in-wave online-softmax merge across the 4 position groups (xor 16, 32)
#pragma unroll
  for (int off = 16; off <= 32; off <<= 1) {
#pragma unroll
    for (int g = 0; g < G_; ++g) {
      float mo = __shfl_xor(m[g], off);
      float lo = __shfl_xor(l[g], off);
      float M  = fmaxf(m[g], mo);
      float fa = __expf(m[g] - M);
      float fb = __expf(mo - M);
      l[g] = l[g] * fa + lo * fb;
      m[g] = M;
#pragma unroll
      for (int j = 0; j < 8; ++j) {
        float ao = __shfl_xor(acc[g][j], off);
        acc[g][j] = acc[g][j] * fa + ao * fb;
      }
    }
  }

  if (lane < 16) {
#pragma unroll
    for (int g = 0; g < G_; ++g) {
      float* op = opart + (size_t)(pidx + g) * D_;
      *(float4*)(op + 4 * dg)      = make_float4(acc[g][0], acc[g][1], acc[g][2], acc[g][3]);
      *(float4*)(op + 64 + 4 * dg) = make_float4(acc[g][4], acc[g][5], acc[g][6], acc[g][7]);
      if (lane == 0) ml[pidx + g] = make_float2(m[g], l[g]);
    }
  }
}

// Kernel 3: merge partitions, normalize, write output.
__global__ void attn_reduce_kernel(const float* __restrict__ opart,
                                   const float2* __restrict__ ml,
                                   const int* __restrict__ ctxl,
                                   float* __restrict__ out) {
  int bh = blockIdx.x;              // 0..B*H-1
  int b = bh >> 5, h = bh & 31;
  int kvh = h >> 2, g = h & 3;
  int d = threadIdx.x;              // 0..127
  int seq = seq_len_of(ctxl[b]);
  int nlive = (seq + PARTN_ - 1) / PARTN_;
  int base = (b * KVH_ + kvh) * NP_;

  float M = -1e30f;
  for (int p = 0; p < nlive; ++p) M = fmaxf(M, ml[(base + p) * G_ + g].x);
  float L = 0.f, O = 0.f;
  for (int p = 0; p < nlive; ++p) {
    float2 mlv = ml[(base + p) * G_ + g];
    float f = __expf(mlv.x - M);
    L += mlv.y * f;
    O += opart[(size_t)((base + p) * G_ + g) * D_ + d] * f;
  }
  out[b * (H_ * D_) + h * D_ + d] = O / L;
}

extern "C" void kernel_launch(void* const* d_in, const int* in_sizes, int n_in,
                              void* d_out, int out_size, void* d_ws, size_t ws_size,
                              hipStream_t stream) {
  const float* q    = (const float*)d_in[0];
  const float* k    = (const float*)d_in[1];
  const float* v    = (const float*)d_in[2];
  const float* kc   = (const float*)d_in[3];
  const float* vc   = (const float*)d_in[4];
  const int*   btab = (const int*)d_in[5];
  const int*   ctxl = (const int*)d_in[6];
  float* out = (float*)d_out;

  float*  tab   = (float*)d_ws;                                  // 2 MB
  float*  opart = tab + (size_t)T_ * 64 * 2;                     // 32 MB
  float2* ml    = (float2*)(opart + (size_t)B_ * KVH_ * NP_ * G_ * D_); // 512 KB

  rope_table_kernel<<<(T_ * 64 + 255) / 256, 256, 0, stream>>>(tab);
  attn_partial_kernel<<<B_ * NP_, 512, 0, stream>>>(
      q, k, v, kc, vc, btab, ctxl, tab, opart, ml);
  attn_reduce_kernel<<<B_ * H_, D_, 0, stream>>>(opart, ml, ctxl, out);
}

// Round 8
// 171.458 us; speedup vs baseline: 1.8419x; 1.8419x over previous
//
#include <hip/hip_runtime.h>
#include <math.h>
#include <stdint.h>

#define B_      16
#define H_      32
#define KVH_    8
#define G_      4
#define D_      128
#define BS_     16
#define L_      4096
#define MAXB_   256
#define T_      4096
#define PARTN_  32            // tokens per partition (one block)
#define NP_     128           // partitions per sequence
#define GT_     4             // tokens per staged group
#define TPADF_  1032          // floats per token in LDS (1024 + 8 pad)
#define SCALE_  0.08838834764831843f

__device__ __forceinline__ int seq_len_of(int ctx) {
  return (ctx >= L_) ? (L_ - BS_ + (ctx & (BS_ - 1)) + 1) : (ctx + 1);
}

// async global->LDS, 16B per lane; LDS dest is wave-uniform base + lane*16,
// global src is per-lane (must be passed with the lane offset included).
__device__ __forceinline__ void gload16(const float* g, float* l) {
  __builtin_amdgcn_global_load_lds(
      (const __attribute__((address_space(1))) void*)(uintptr_t)g,
      (__attribute__((address_space(3))) void*)(uintptr_t)l, 16, 0, 0);
}

// Kernel 1: RoPE table, [T][64] pairs of (cos, sin) interleaved.
__global__ void rope_table_kernel(float* __restrict__ tab) {
  int idx = blockIdx.x * blockDim.x + threadIdx.x;
  if (idx >= T_ * 64) return;
  int t = idx >> 6, i = idx & 63;
  double inv = pow(10000.0, -(double)(2 * i) / 128.0);
  float ang = (float)t * (float)inv;   // f32 argument, like the reference
  double a = (double)ang;
  tab[2 * idx]     = (float)cos(a);
  tab[2 * idx + 1] = (float)sin(a);
}

// Kernel 2: one 512-thread block (8 waves) per (b, 32-token partition),
// covering ALL 8 kv-heads -> every global K/V read is a contiguous 16 KB
// stream. Per 4-token group: issue next group's global_load_lds (async,
// no VGPR round-trip), compute current group from LDS, barrier. Wave w
// computes kvh w: 16 lanes/token, lane dg holds dims [4dg..4dg+3] and
// [64+4dg..64+4dg+3] (RoPE-pair local).

#define STAGE(buf, gi)                                                      \
  {                                                                         \
    int blk_ = ((gi) & 4) ? bt.y : bt.x;                                    \
    size_t off_ = (size_t)(blk_ * BS_ + (((gi) << 2) & 15)) * (KVH_ * D_)   \
                + lane * 4;                                                 \
    gload16(kc + off_ + c0 * 256, &lds[buf][0][dK0]);                       \
    gload16(kc + off_ + c1 * 256, &lds[buf][0][dK1]);                       \
    gload16(vc + off_ + c0 * 256, &lds[buf][1][dK0]);                       \
    gload16(vc + off_ + c1 * 256, &lds[buf][1][dK1]);                       \
  }

__global__ __launch_bounds__(512) void attn_partial_kernel(
    const float* __restrict__ q, const float* __restrict__ knew,
    const float* __restrict__ vnew, const float* __restrict__ kc,
    const float* __restrict__ vc, const int* __restrict__ btab,
    const int* __restrict__ ctxl, const float* __restrict__ tab,
    float* __restrict__ opart, float2* __restrict__ ml) {
  int bid  = blockIdx.x;
  int part = bid & (NP_ - 1);
  int b    = bid >> 7;                   // NP_ == 128

  int seq = seq_len_of(ctxl[b]);
  int t0 = part * PARTN_;
  if (t0 >= seq) return;                 // block-uniform (before any barrier)
  int t1 = min(t0 + PARTN_, seq);
  int posq = seq - 1;
  int nG = (t1 - t0 + GT_ - 1) >> 2;

  int tid  = threadIdx.x;
  int kvh  = tid >> 6;                   // wave index == kv head
  int lane = tid & 63;
  int tsub = lane >> 4;
  int dg   = lane & 15;
  int pidx = ((b * KVH_ + kvh) * NP_ + part) * G_;

  // two cache-block ids cover the 32-token partition
  int2 bt = *(const int2*)(btab + b * MAXB_ + (t0 >> 4));

  // this wave's two 1KB chunks (of 16) per K/V group, and their LDS slots
  const int c0 = 2 * kvh, c1 = 2 * kvh + 1;
  const int dK0 = (c0 >> 2) * TPADF_ + (c0 & 3) * 256;
  const int dK1 = (c1 >> 2) * TPADF_ + (c1 & 3) * 256;

  __shared__ float lds[2][2][GT_ * TPADF_];   // [buf][K/V][tok*TPADF_+f]

  const float4* tab4 = (const float4*)tab;

  // roped + scaled q fragments for the 4 heads of this kv group
  float q1[G_][4], q2[G_][4];
  {
    float4 cq0 = tab4[posq * 32 + 2 * dg];
    float4 cq1 = tab4[posq * 32 + 2 * dg + 1];
#pragma unroll
    for (int g = 0; g < G_; ++g) {
      const float* qp = q + b * (H_ * D_) + (kvh * G_ + g) * D_;
      float4 a  = *(const float4*)(qp + 4 * dg);
      float4 bq = *(const float4*)(qp + 64 + 4 * dg);
      q1[g][0] = (a.x * cq0.x - bq.x * cq0.y) * SCALE_;
      q2[g][0] = (bq.x * cq0.x + a.x * cq0.y) * SCALE_;
      q1[g][1] = (a.y * cq0.z - bq.y * cq0.w) * SCALE_;
      q2[g][1] = (bq.y * cq0.z + a.y * cq0.w) * SCALE_;
      q1[g][2] = (a.z * cq1.x - bq.z * cq1.y) * SCALE_;
      q2[g][2] = (bq.z * cq1.x + a.z * cq1.y) * SCALE_;
      q1[g][3] = (a.w * cq1.z - bq.w * cq1.w) * SCALE_;
      q2[g][3] = (bq.w * cq1.z + a.w * cq1.w) * SCALE_;
    }
  }

  float m[G_], l[G_], acc[G_][8];
#pragma unroll
  for (int g = 0; g < G_; ++g) {
    m[g] = -1e30f; l[g] = 0.f;
#pragma unroll
    for (int j = 0; j < 8; ++j) acc[g][j] = 0.f;
  }

  // main loop: prologue stage; then {issue next (async), compute cur, bar}
  STAGE(0, 0);
  __syncthreads();                        // drains vmcnt(0): buf0 ready
  int cur = 0;
  for (int gi = 0; gi < nG; ++gi) {
    if (gi + 1 < nG) STAGE(cur ^ 1, gi + 1);   // block-uniform condition
    {
      int tt = t0 + (gi << 2) + tsub;
      int aK = tsub * TPADF_ + kvh * D_ + 4 * dg;
      float4 ka = *(const float4*)&lds[cur][0][aK];
      float4 kb = *(const float4*)&lds[cur][0][aK + 64];
      float4 va = *(const float4*)&lds[cur][1][aK];
      float4 vb = *(const float4*)&lds[cur][1][aK + 64];
      float4 cc0 = tab4[tt * 32 + 2 * dg];
      float4 cc1 = tab4[tt * 32 + 2 * dg + 1];
      float kr1[4], kr2[4];
      kr1[0] = ka.x * cc0.x - kb.x * cc0.y;  kr2[0] = kb.x * cc0.x + ka.x * cc0.y;
      kr1[1] = ka.y * cc0.z - kb.y * cc0.w;  kr2[1] = kb.y * cc0.z + ka.y * cc0.w;
      kr1[2] = ka.z * cc1.x - kb.z * cc1.y;  kr2[2] = kb.z * cc1.x + ka.z * cc1.y;
      kr1[3] = ka.w * cc1.z - kb.w * cc1.w;  kr2[3] = kb.w * cc1.z + ka.w * cc1.w;
      bool valid = (tt < t1) & (tt != posq);
      float s[G_];
#pragma unroll
      for (int g = 0; g < G_; ++g) {
        s[g] = kr1[0] * q1[g][0] + kr2[0] * q2[g][0]
             + kr1[1] * q1[g][1] + kr2[1] * q2[g][1]
             + kr1[2] * q1[g][2] + kr2[2] * q2[g][2]
             + kr1[3] * q1[g][3] + kr2[3] * q2[g][3];
      }
#pragma unroll
      for (int off = 1; off <= 8; off <<= 1) {
#pragma unroll
        for (int g = 0; g < G_; ++g) s[g] += __shfl_xor(s[g], off);
      }
#pragma unroll
      for (int g = 0; g < G_; ++g) {
        float sv   = valid ? s[g] : -1e30f;
        float mn   = fmaxf(m[g], sv);
        float corr = __expf(m[g] - mn);
        float p    = __expf(sv - mn);
        p = valid ? p : 0.0f;
        m[g] = mn;
        l[g] = l[g] * corr + p;
        acc[g][0] = acc[g][0] * corr + p * va.x;
        acc[g][1] = acc[g][1] * corr + p * va.y;
        acc[g][2] = acc[g][2] * corr + p * va.z;
        acc[g][3] = acc[g][3] * corr + p * va.w;
        acc[g][4] = acc[g][4] * corr + p * vb.x;
        acc[g][5] = acc[g][5] * corr + p * vb.y;
        acc[g][6] = acc[g][6] * corr + p * vb.z;
        acc[g][7] = acc[g][7] * corr + p * vb.w;
      }
    }
    __syncthreads();                     // drains next-group loads; frees cur
    cur ^= 1;
  }

  // current-token contribution (the one partition owning posq), lanes 0-15
  if (lane < 16 && posq >= t0 && posq < t1) {
    const float* kp = knew + (b * KVH_ + kvh) * D_;
    float4 xa = *(const float4*)(kp + 4 * dg);
    float4 xb = *(const float4*)(kp + 64 + 4 * dg);
    float4 p0 = tab4[posq * 32 + 2 * dg];
    float4 p1 = tab4[posq * 32 + 2 * dg + 1];
    float kr1[4], kr2[4];
    kr1[0] = xa.x * p0.x - xb.x * p0.y;  kr2[0] = xb.x * p0.x + xa.x * p0.y;
    kr1[1] = xa.y * p0.z - xb.y * p0.w;  kr2[1] = xb.y * p0.z + xa.y * p0.w;
    kr1[2] = xa.z * p1.x - xb.z * p1.y;  kr2[2] = xb.z * p1.x + xa.z * p1.y;
    kr1[3] = xa.w * p1.z - xb.w * p1.w;  kr2[3] = xb.w * p1.z + xa.w * p1.w;
    const float* vp = vnew + (b * KVH_ + kvh) * D_;
    float4 va = *(const float4*)(vp + 4 * dg);
    float4 vb = *(const float4*)(vp + 64 + 4 * dg);
    float s[G_];
#pragma unroll
    for (int g = 0; g < G_; ++g) {
      s[g] = kr1[0] * q1[g][0] + kr2[0] * q2[g][0]
           + kr1[1] * q1[g][1] + kr2[1] * q2[g][1]
           + kr1[2] * q1[g][2] + kr2[2] * q2[g][2]
           + kr1[3] * q1[g][3] + kr2[3] * q2[g][3];
    }
#pragma unroll
    for (int off = 1; off <= 8; off <<= 1) {
#pragma unroll
      for (int g = 0; g < G_; ++g) s[g] += __shfl_xor(s[g], off);
    }
#pragma unroll
    for (int g = 0; g < G_; ++g) {
      float sv   = s[g];
      float mn   = fmaxf(m[g], sv);
      float corr = __expf(m[g] - mn);
      float p    = __expf(sv - mn);
      m[g] = mn;
      l[g] = l[g] * corr + p;
      acc[g][0] = acc[g][0] * corr + p * va.x;
      acc[g][1] = acc[g][1] * corr + p * va.y;
      acc[g][2] = acc[g][2] * corr + p * va.z;
      acc[g][3] = acc[g][3] * corr + p * va.w;
      acc[g][4] = acc[g][4] * corr + p * vb.x;
      acc[g][5] = acc[g][5] * corr + p * vb.y;
      acc[g][6] = acc[g][6] * corr + p * vb.z;
      acc[g][7] = acc[g][7] * corr + p * vb.w;
    }
  }

  // in-wave online-softmax merge across the 4 token groups (xor 16, 32)
#pragma unroll
  for (int off = 16; off <= 32; off <<= 1) {
#pragma unroll
    for (int g = 0; g < G_; ++g) {
      float mo = __shfl_xor(m[g], off);
      float lo = __shfl_xor(l[g], off);
      float M  = fmaxf(m[g], mo);
      float fa = __expf(m[g] - M);
      float fb = __expf(mo - M);
      l[g] = l[g] * fa + lo * fb;
      m[g] = M;
#pragma unroll
      for (int j = 0; j < 8; ++j) {
        float ao = __shfl_xor(acc[g][j], off);
        acc[g][j] = acc[g][j] * fa + ao * fb;
      }
    }
  }

  if (lane < 16) {
#pragma unroll
    for (int g = 0; g < G_; ++g) {
      float* op = opart + (size_t)(pidx + g) * D_;
      *(float4*)(op + 4 * dg)      = make_float4(acc[g][0], acc[g][1], acc[g][2], acc[g][3]);
      *(float4*)(op + 64 + 4 * dg) = make_float4(acc[g][4], acc[g][5], acc[g][6], acc[g][7]);
      if (lane == 0) ml[pidx + g] = make_float2(m[g], l[g]);
    }
  }
}

// Kernel 3: merge partitions, normalize, write output.
__global__ void attn_reduce_kernel(const float* __restrict__ opart,
                                   const float2* __restrict__ ml,
                                   const int* __restrict__ ctxl,
                                   float* __restrict__ out) {
  int bh = blockIdx.x;              // 0..B*H-1
  int b = bh >> 5, h = bh & 31;
  int kvh = h >> 2, g = h & 3;
  int d = threadIdx.x;              // 0..127
  int seq = seq_len_of(ctxl[b]);
  int nlive = (seq + PARTN_ - 1) / PARTN_;
  int base = (b * KVH_ + kvh) * NP_;

  float M = -1e30f;
  for (int p = 0; p < nlive; ++p) M = fmaxf(M, ml[(base + p) * G_ + g].x);
  float L = 0.f, O = 0.f;
  for (int p = 0; p < nlive; ++p) {
    float2 mlv = ml[(base + p) * G_ + g];
    float f = __expf(mlv.x - M);
    L += mlv.y * f;
    O += opart[(size_t)((base + p) * G_ + g) * D_ + d] * f;
  }
  out[b * (H_ * D_) + h * D_ + d] = O / L;
}

extern "C" void kernel_launch(void* const* d_in, const int* in_sizes, int n_in,
                              void* d_out, int out_size, void* d_ws, size_t ws_size,
                              hipStream_t stream) {
  const float* q    = (const float*)d_in[0];
  const float* k    = (const float*)d_in[1];
  const float* v    = (const float*)d_in[2];
  const float* kc   = (const float*)d_in[3];
  const float* vc   = (const float*)d_in[4];
  const int*   btab = (const int*)d_in[5];
  const int*   ctxl = (const int*)d_in[6];
  float* out = (float*)d_out;

  float*  tab   = (float*)d_ws;                                  // 2 MB
  float*  opart = tab + (size_t)T_ * 64 * 2;                     // 33.5 MB
  float2* ml    = (float2*)(opart + (size_t)B_ * KVH_ * NP_ * G_ * D_); // 512 KB

  rope_table_kernel<<<(T_ * 64 + 255) / 256, 256, 0, stream>>>(tab);
  attn_partial_kernel<<<B_ * NP_, 512, 0, stream>>>(
      q, k, v, kc, vc, btab, ctxl, tab, opart, ml);
  attn_reduce_kernel<<<B_ * H_, D_, 0, stream>>>(opart, ml, ctxl, out);
}

// Round 10
// 119.219 us; speedup vs baseline: 2.6490x; 1.4382x over previous
//
#include <hip/hip_runtime.h>
#include <math.h>

#define B_      16
#define H_      32
#define KVH_    8
#define G_      4
#define D_      128
#define BS_     16
#define L_      4096
#define MAXB_   256
#define T_      4096
#define NPART_  16
#define PART_   256
#define SCALE_  0.08838834764831843f

__device__ __forceinline__ int seq_len_of(int ctx) {
  return (ctx >= L_) ? (L_ - BS_ + (ctx & (BS_ - 1)) + 1) : (ctx + 1);
}

// Partial attention per (b, kvh, 256-token partition). 256 threads = 4 waves;
// 16 lanes per position (4 positions/wave/iter, stride 16). Lane dg holds dims
// [4dg..4dg+3] and [64+4dg..64+4dg+3] (4 RoPE pairs, lane-local). Cos/sin
// initialized ONCE per lane with the exact table math (f64 pow -> f32-rounded
// angle -> f64 sincos; proven absmax 9.8e-4) and advanced in-register by
// angle-addition (rotation by 16*theta per iteration). Depth-1 A/B register
// prefetch; block-table slice staged in LDS. No separate table kernel.

#define LOADK(P, tt)                                                        \
  {                                                                         \
    int blk_  = sblk[((tt) - t0) >> 4];                                     \
    int base_ = ((blk_ * BS_ + ((tt) & (BS_ - 1))) * KVH_ + kvh) * D_;      \
    const float4* kc4_ = (const float4*)(kc + base_);                       \
    const float4* vc4_ = (const float4*)(vc + base_);                       \
    P##ka = kc4_[dg];      P##kb = kc4_[16 + dg];                           \
    P##va = vc4_[dg];      P##vb = vc4_[16 + dg];                           \
  }

#define COMPUTE(P, tt)                                                      \
  {                                                                         \
    float kr1[4], kr2[4];                                                   \
    kr1[0] = P##ka.x * cc0.x - P##kb.x * cc0.y;                             \
    kr2[0] = P##kb.x * cc0.x + P##ka.x * cc0.y;                             \
    kr1[1] = P##ka.y * cc0.z - P##kb.y * cc0.w;                             \
    kr2[1] = P##kb.y * cc0.z + P##ka.y * cc0.w;                             \
    kr1[2] = P##ka.z * cc1.x - P##kb.z * cc1.y;                             \
    kr2[2] = P##kb.z * cc1.x + P##ka.z * cc1.y;                             \
    kr1[3] = P##ka.w * cc1.z - P##kb.w * cc1.w;                             \
    kr2[3] = P##kb.w * cc1.z + P##ka.w * cc1.w;                             \
    bool valid_ = ((tt) != posq);                                           \
    float s[G_];                                                            \
    _Pragma("unroll")                                                       \
    for (int g = 0; g < G_; ++g) {                                          \
      s[g] = kr1[0] * q1[g][0] + kr2[0] * q2[g][0]                          \
           + kr1[1] * q1[g][1] + kr2[1] * q2[g][1]                          \
           + kr1[2] * q1[g][2] + kr2[2] * q2[g][2]                          \
           + kr1[3] * q1[g][3] + kr2[3] * q2[g][3];                         \
    }                                                                       \
    _Pragma("unroll")                                                       \
    for (int off = 1; off <= 8; off <<= 1) {                                \
      _Pragma("unroll")                                                     \
      for (int g = 0; g < G_; ++g) s[g] += __shfl_xor(s[g], off);           \
    }                                                                       \
    _Pragma("unroll")                                                       \
    for (int g = 0; g < G_; ++g) {                                          \
      float sv   = valid_ ? s[g] : -1e30f;                                  \
      float mn   = fmaxf(m[g], sv);                                         \
      float corr = __expf(m[g] - mn);                                       \
      float p    = __expf(sv - mn);                                         \
      p = valid_ ? p : 0.0f;                                                \
      m[g] = mn;                                                            \
      l[g] = l[g] * corr + p;                                               \
      acc[g][0] = acc[g][0] * corr + p * P##va.x;                           \
      acc[g][1] = acc[g][1] * corr + p * P##va.y;                           \
      acc[g][2] = acc[g][2] * corr + p * P##va.z;                           \
      acc[g][3] = acc[g][3] * corr + p * P##va.w;                           \
      acc[g][4] = acc[g][4] * corr + p * P##vb.x;                           \
      acc[g][5] = acc[g][5] * corr + p * P##vb.y;                           \
      acc[g][6] = acc[g][6] * corr + p * P##vb.z;                           \
      acc[g][7] = acc[g][7] * corr + p * P##vb.w;                           \
    }                                                                       \
    { /* advance cos/sin by 16*theta (angle addition) */                    \
      float nc_;                                                            \
      nc_ = cc0.x * r0.x - cc0.y * r0.y;                                    \
      cc0.y = cc0.y * r0.x + cc0.x * r0.y; cc0.x = nc_;                     \
      nc_ = cc0.z * r0.z - cc0.w * r0.w;                                    \
      cc0.w = cc0.w * r0.z + cc0.z * r0.w; cc0.z = nc_;                     \
      nc_ = cc1.x * r1.x - cc1.y * r1.y;                                    \
      cc1.y = cc1.y * r1.x + cc1.x * r1.y; cc1.x = nc_;                     \
      nc_ = cc1.z * r1.z - cc1.w * r1.w;                                    \
      cc1.w = cc1.w * r1.z + cc1.z * r1.w; cc1.z = nc_;                     \
    }                                                                       \
  }

__global__ __launch_bounds__(256) void attn_partial_kernel(
    const float* __restrict__ q, const float* __restrict__ knew,
    const float* __restrict__ vnew, const float* __restrict__ kc,
    const float* __restrict__ vc, const int* __restrict__ btab,
    const int* __restrict__ ctxl,
    float* __restrict__ opart, float2* __restrict__ ml) {
  int bid  = blockIdx.x;
  int part = bid & (NPART_ - 1);
  int kvh  = (bid >> 4) & (KVH_ - 1);
  int b    = bid >> 7;

  int seq = seq_len_of(ctxl[b]);
  int t0 = part * PART_;
  if (t0 >= seq) return;                 // uniform per block: safe early exit
  int t1 = min(t0 + PART_, seq);
  int posq = seq - 1;

  int lane = threadIdx.x & 63;
  int wave = threadIdx.x >> 6;
  int tsub = lane >> 4;
  int dg   = lane & 15;

  // block table slice for this partition -> LDS (index == (t - t0) >> 4)
  __shared__ int sblk[PART_ / BS_];
  if (threadIdx.x < PART_ / BS_)
    sblk[threadIdx.x] = btab[b * MAXB_ + (t0 >> 4) + threadIdx.x];
  __syncthreads();

  // per-lane cos/sin (pairs 4dg..4dg+3): at tstart (cc), rotation by 16
  // steps (r), at posq (cq). Exact table math: f64 pow -> f32-rounded
  // angle -> f64 sincos. Computed once per lane.
  int tstart = t0 + 4 * wave + tsub;
  float4 cc0, cc1, r0, r1, cq0, cq1;
  {
    float ft = (float)tstart, fq = (float)posq;
    float cs[3][8];
#pragma unroll
    for (int j = 0; j < 4; ++j) {
      double invd = pow(10000.0, -(double)(8 * dg + 2 * j) / 128.0);
      float invf = (float)invd;
      float angs[3] = {ft * invf, 16.0f * invf, fq * invf};
#pragma unroll
      for (int u = 0; u < 3; ++u) {
        double sn, csn;
        sincos((double)angs[u], &sn, &csn);
        cs[u][2 * j]     = (float)csn;
        cs[u][2 * j + 1] = (float)sn;
      }
    }
    cc0 = make_float4(cs[0][0], cs[0][1], cs[0][2], cs[0][3]);
    cc1 = make_float4(cs[0][4], cs[0][5], cs[0][6], cs[0][7]);
    r0  = make_float4(cs[1][0], cs[1][1], cs[1][2], cs[1][3]);
    r1  = make_float4(cs[1][4], cs[1][5], cs[1][6], cs[1][7]);
    cq0 = make_float4(cs[2][0], cs[2][1], cs[2][2], cs[2][3]);
    cq1 = make_float4(cs[2][4], cs[2][5], cs[2][6], cs[2][7]);
  }

  // roped + scaled q fragments for the 4 heads of this kv group
  float q1[G_][4], q2[G_][4];
#pragma unroll
  for (int g = 0; g < G_; ++g) {
    const float* qp = q + b * (H_ * D_) + (kvh * G_ + g) * D_;
    float4 a  = *(const float4*)(qp + 4 * dg);
    float4 bq = *(const float4*)(qp + 64 + 4 * dg);
    q1[g][0] = (a.x * cq0.x - bq.x * cq0.y) * SCALE_;
    q2[g][0] = (bq.x * cq0.x + a.x * cq0.y) * SCALE_;
    q1[g][1] = (a.y * cq0.z - bq.y * cq0.w) * SCALE_;
    q2[g][1] = (bq.y * cq0.z + a.y * cq0.w) * SCALE_;
    q1[g][2] = (a.z * cq1.x - bq.z * cq1.y) * SCALE_;
    q2[g][2] = (bq.z * cq1.x + a.z * cq1.y) * SCALE_;
    q1[g][3] = (a.w * cq1.z - bq.w * cq1.w) * SCALE_;
    q2[g][3] = (bq.w * cq1.z + a.w * cq1.w) * SCALE_;
  }

  float m[G_], l[G_], acc[G_][8];
#pragma unroll
  for (int g = 0; g < G_; ++g) {
    m[g] = -1e30f; l[g] = 0.f;
#pragma unroll
    for (int j = 0; j < 8; ++j) acc[g][j] = 0.f;
  }

  // depth-1 software pipeline (named A/B buffers), as in the 119us kernel
  {
    float4 Aka, Akb, Ava, Avb;
    float4 Bka, Bkb, Bva, Bvb;
    int t = tstart;                      // group-uniform; shuffles in-group
    if (t < t1) {
      LOADK(A, t);
      while (1) {
        int t2 = t + 16;
        if (t2 < t1) LOADK(B, t2);
        COMPUTE(A, t);
        t = t2;
        if (t >= t1) break;
        t2 = t + 16;
        if (t2 < t1) LOADK(A, t2);
        COMPUTE(B, t);
        t = t2;
        if (t >= t1) break;
      }
    }
  }

  // current-token contribution: ONLY WAVE 0, lanes 0-15 (added exactly once;
  // round 9's `lane < 16` counted it per-wave -> 4x, absmax 0.465)
  if (threadIdx.x < 16 && posq >= t0 && posq < t1) {
    const float* kp = knew + (b * KVH_ + kvh) * D_;
    float4 xa = *(const float4*)(kp + 4 * dg);
    float4 xb = *(const float4*)(kp + 64 + 4 * dg);
    float kr1[4], kr2[4];
    kr1[0] = xa.x * cq0.x - xb.x * cq0.y;  kr2[0] = xb.x * cq0.x + xa.x * cq0.y;
    kr1[1] = xa.y * cq0.z - xb.y * cq0.w;  kr2[1] = xb.y * cq0.z + xa.y * cq0.w;
    kr1[2] = xa.z * cq1.x - xb.z * cq1.y;  kr2[2] = xb.z * cq1.x + xa.z * cq1.y;
    kr1[3] = xa.w * cq1.z - xb.w * cq1.w;  kr2[3] = xb.w * cq1.z + xa.w * cq1.w;
    const float* vp = vnew + (b * KVH_ + kvh) * D_;
    float4 va_ = *(const float4*)(vp + 4 * dg);
    float4 vb_ = *(const float4*)(vp + 64 + 4 * dg);
    float s[G_];
#pragma unroll
    for (int g = 0; g < G_; ++g) {
      s[g] = kr1[0] * q1[g][0] + kr2[0] * q2[g][0]
           + kr1[1] * q1[g][1] + kr2[1] * q2[g][1]
           + kr1[2] * q1[g][2] + kr2[2] * q2[g][2]
           + kr1[3] * q1[g][3] + kr2[3] * q2[g][3];
    }
#pragma unroll
    for (int off = 1; off <= 8; off <<= 1) {
#pragma unroll
      for (int g = 0; g < G_; ++g) s[g] += __shfl_xor(s[g], off);
    }
#pragma unroll
    for (int g = 0; g < G_; ++g) {
      float sv   = s[g];
      float mn   = fmaxf(m[g], sv);
      float corr = __expf(m[g] - mn);
      float p    = __expf(sv - mn);
      m[g] = mn;
      l[g] = l[g] * corr + p;
      acc[g][0] = acc[g][0] * corr + p * va_.x;
      acc[g][1] = acc[g][1] * corr + p * va_.y;
      acc[g][2] = acc[g][2] * corr + p * va_.z;
      acc[g][3] = acc[g][3] * corr + p * va_.w;
      acc[g][4] = acc[g][4] * corr + p * vb_.x;
      acc[g][5] = acc[g][5] * corr + p * vb_.y;
      acc[g][6] = acc[g][6] * corr + p * vb_.z;
      acc[g][7] = acc[g][7] * corr + p * vb_.w;
    }
  }

  // online-softmax state merge across lane groups (xor 16, 32), then waves via LDS
  auto merge_off = [&](int off) {
#pragma unroll
    for (int g = 0; g < G_; ++g) {
      float mo = __shfl_xor(m[g], off);
      float lo = __shfl_xor(l[g], off);
      float M  = fmaxf(m[g], mo);
      float fa = __expf(m[g] - M);
      float fb = __expf(mo - M);
      l[g] = l[g] * fa + lo * fb;
      m[g] = M;
#pragma unroll
      for (int j = 0; j < 8; ++j) {
        float ao = __shfl_xor(acc[g][j], off);
        acc[g][j] = acc[g][j] * fa + ao * fb;
      }
    }
  };
  merge_off(16);
  merge_off(32);

  __shared__ float  lds_acc[4][G_][D_];
  __shared__ float2 lds_ml[4][G_];
  if (lane < 16) {
#pragma unroll
    for (int g = 0; g < G_; ++g) {
#pragma unroll
      for (int j = 0; j < 8; ++j) {
        int dim = (j < 4) ? (4 * dg + j) : (64 + 4 * dg + (j - 4));
        lds_acc[wave][g][dim] = acc[g][j];
      }
      if (lane == 0) lds_ml[wave][g] = make_float2(m[g], l[g]);
    }
  }
  __syncthreads();
  if (wave == 0) {
    int w = tsub;
#pragma unroll
    for (int g = 0; g < G_; ++g) {
      float2 t2 = lds_ml[w][g];
      m[g] = t2.x; l[g] = t2.y;
#pragma unroll
      for (int j = 0; j < 8; ++j) {
        int dim = (j < 4) ? (4 * dg + j) : (64 + 4 * dg + (j - 4));
        acc[g][j] = lds_acc[w][g][dim];
      }
    }
    merge_off(16);
    merge_off(32);
    if (lane < 16) {
#pragma unroll
      for (int g = 0; g < G_; ++g) {
        float* op = opart + (size_t)((bid)*G_ + g) * D_;
#pragma unroll
        for (int j = 0; j < 8; ++j) {
          int dim = (j < 4) ? (4 * dg + j) : (64 + 4 * dg + (j - 4));
          op[dim] = acc[g][j];
        }
        if (lane == 0) ml[bid * G_ + g] = make_float2(m[g], l[g]);
      }
    }
  }
}

// Merge partitions, normalize, write output.
__global__ void attn_reduce_kernel(const float* __restrict__ opart,
                                   const float2* __restrict__ ml,
                                   const int* __restrict__ ctxl,
                                   float* __restrict__ out) {
  int bh = blockIdx.x;              // 0..B*H-1
  int b = bh >> 5, h = bh & 31;
  int kvh = h >> 2, g = h & 3;
  int d = threadIdx.x;              // 0..127
  int seq = seq_len_of(ctxl[b]);
  int nlive = (seq + PART_ - 1) / PART_;
  int base = (b * KVH_ + kvh) * NPART_;

  float M = -1e30f;
  for (int p = 0; p < nlive; ++p) M = fmaxf(M, ml[(base + p) * G_ + g].x);
  float L = 0.f, O = 0.f;
  for (int p = 0; p < nlive; ++p) {
    float2 mlv = ml[(base + p) * G_ + g];
    float f = __expf(mlv.x - M);
    L += mlv.y * f;
    O += opart[(size_t)((base + p) * G_ + g) * D_ + d] * f;
  }
  out[b * (H_ * D_) + h * D_ + d] = O / L;
}

extern "C" void kernel_launch(void* const* d_in, const int* in_sizes, int n_in,
                              void* d_out, int out_size, void* d_ws, size_t ws_size,
                              hipStream_t stream) {
  const float* q    = (const float*)d_in[0];
  const float* k    = (const float*)d_in[1];
  const float* v    = (const float*)d_in[2];
  const float* kc   = (const float*)d_in[3];
  const float* vc   = (const float*)d_in[4];
  const int*   btab = (const int*)d_in[5];
  const int*   ctxl = (const int*)d_in[6];
  float* out = (float*)d_out;

  float*  opart = (float*)d_ws;                                  // 4 MB
  float2* ml    = (float2*)(opart + (size_t)B_ * KVH_ * NPART_ * G_ * D_); // 64 KB

  attn_partial_kernel<<<B_ * KVH_ * NPART_, 256, 0, stream>>>(
      q, k, v, kc, vc, btab, ctxl, opart, ml);
  attn_reduce_kernel<<<B_ * H_, D_, 0, stream>>>(opart, ml, ctxl, out);
}